// Round 10
// baseline (346.622 us; speedup 1.0000x reference)
//
#include <hip/hip_runtime.h>
#include <hip/hip_bf16.h>

typedef __attribute__((ext_vector_type(8))) short short8;
typedef __attribute__((ext_vector_type(4))) short short4v;
typedef __attribute__((ext_vector_type(4))) float f32x4;

#define MFMA16(a, b, c) __builtin_amdgcn_mfma_f32_16x16x32_bf16(a, b, c, 0, 0, 0)

__device__ __forceinline__ unsigned short f2bf(float f) {
    union { __hip_bfloat16 h; unsigned short u; } v;
    v.h = __float2bfloat16(f);
    return v.u;
}

__device__ __forceinline__ short8 pack8(float4 a, float4 b) {
    short8 p;
    p[0] = (short)f2bf(a.x); p[1] = (short)f2bf(a.y);
    p[2] = (short)f2bf(a.z); p[3] = (short)f2bf(a.w);
    p[4] = (short)f2bf(b.x); p[5] = (short)f2bf(b.y);
    p[6] = (short)f2bf(b.z); p[7] = (short)f2bf(b.w);
    return p;
}

// XOR-swizzled LDS indexing (T2): linear rows, byte ^= (row&N)<<4.
__device__ __forceinline__ int swz64(int row, int bytecol) {   // 64-short rows
    return row * 64 + ((bytecol ^ ((row & 7) << 4)) >> 1);
}
__device__ __forceinline__ int swz256(int row, int bytecol) {  // 256-short rows
    return row * 256 + ((bytecol ^ ((row & 7) << 4)) >> 1);
}
__device__ __forceinline__ int swz32(int row, int bytecol) {   // 32-short rows
    return row * 32 + ((bytecol ^ ((row & 3) << 4)) >> 1);
}

// global -> LDS direct copy, 16B/lane (m97 recipe; source pre-swizzled).
__device__ __forceinline__ void async16(void* lds_uniform, const void* gsrc) {
    __builtin_amdgcn_global_load_lds(
        (const __attribute__((address_space(1))) unsigned int*)gsrc,
        (__attribute__((address_space(3))) unsigned int*)lds_uniform,
        16, 0, 0);
}

// ---------------------------------------------------------------------------
// Weight prep: wt[m][n][k'] = W_m[k][n] bf16; swz: k' = k ^ ((n&7)*8).
// ---------------------------------------------------------------------------
__global__ __launch_bounds__(256) void wprep(
    const float* __restrict__ Wq, const float* __restrict__ Wk,
    const float* __restrict__ Wv, const float* __restrict__ Wo,
    unsigned short* __restrict__ wt, int swz)
{
    __shared__ float tile[64][65];
    const int bid = blockIdx.x;
    const int m = bid >> 6, tb = bid & 63;
    const int kr = (tb >> 3) << 6, nc = (tb & 7) << 6;
    const float* W = (m == 0) ? Wq : (m == 1) ? Wk : (m == 2) ? Wv : Wo;
    const int tid = threadIdx.x;
    for (int i = tid; i < 4096; i += 256)
        tile[i >> 6][i & 63] = W[(size_t)(kr + (i >> 6)) * 512 + nc + (i & 63)];
    __syncthreads();
    unsigned short* dst = wt + (size_t)m * 262144;
    for (int i = tid; i < 4096; i += 256) {
        const int n = nc + (i >> 6);
        const int e = i & 63;
        const int rsw = swz ? ((n & 7) * 8) : 0;
        dst[(size_t)n * 512 + kr + e] = f2bf(tile[e ^ rsw][i >> 6]);
    }
}

// ---------------------------------------------------------------------------
// X prep: xb[row][e] = bf16(hs[row][e ^ ((row&7)*8)]).
// ---------------------------------------------------------------------------
__global__ __launch_bounds__(256) void xprep(
    const float* __restrict__ hs, unsigned short* __restrict__ xb)
{
    const long long total = 4194304;   // 65536*512/8
    for (long long g = (long long)blockIdx.x * 256 + threadIdx.x; g < total;
         g += (long long)gridDim.x * 256) {
        const int row = (int)(g >> 6);
        const int e0  = ((int)g & 63) * 8;
        const int src = e0 ^ ((row & 7) * 8);
        const float* s = hs + (size_t)row * 512 + src;
        const float4 f0 = *(const float4*)s;
        const float4 f1 = *(const float4*)(s + 4);
        *(short8*)(xb + (size_t)row * 512 + e0) = pack8(f0, f1);
    }
}

// ---------------------------------------------------------------------------
// Single-buffer glds GEMM (round-7 proven: 147 us, MfmaUtil 30%, 0 conflicts).
// 128x128 tile, BK=64, 256 thr = 4 waves (2x2), wave 64x64. A/B PRE-SWIZZLED.
// F32OUT=0: bf16 -> qkvb[3][65536][512]; F32OUT=1: f32 -> of32.
// ---------------------------------------------------------------------------
template<int F32OUT>
__global__ __launch_bounds__(256) void gemm_glds(
    const unsigned short* __restrict__ A,
    const unsigned short* __restrict__ B,
    unsigned short* __restrict__ obf,
    float* __restrict__ of32,
    int nbcnt)
{
    __shared__ unsigned short As[128 * 64];   // 16 KB
    __shared__ unsigned short Bs[128 * 64];   // 16 KB

    const int orig  = blockIdx.x;
    const int chunk = gridDim.x >> 3;
    const int wg = (orig & 7) * chunk + (orig >> 3);
    const int mb = wg / nbcnt;
    const int nb = wg - mb * nbcnt;

    const int tid  = threadIdx.x;
    const int lane = tid & 63;
    const int w    = tid >> 6;
    const int l15  = lane & 15;
    const int hi4  = lane >> 4;
    const int wr   = w >> 1, wc = w & 1;

    f32x4 acc[4][4];
    #pragma unroll
    for (int mt = 0; mt < 4; ++mt)
        #pragma unroll
        for (int nt = 0; nt < 4; ++nt)
            acc[mt][nt] = (f32x4){0.f, 0.f, 0.f, 0.f};

    const char* __restrict__ Ab = (const char*)(A + (size_t)mb * 128 * 512);
    const char* __restrict__ Bb = (const char*)(B + (size_t)nb * 128 * 512);
    const int sbase = w * 4096;               // per-wave LDS byte base

    for (int kb = 0; kb < 512; kb += 64) {
        #pragma unroll
        for (int i = 0; i < 4; ++i) {
            const int sb = sbase + i * 1024;
            const int s  = sb + lane * 16;
            const int row = s >> 7, colb = s & 127;
            const size_t goff = (size_t)row * 1024 + (size_t)kb * 2 + colb;
            async16(&As[sb >> 1], Ab + goff);
            async16(&Bs[sb >> 1], Bb + goff);
        }
        __syncthreads();
        #pragma unroll
        for (int ks = 0; ks < 2; ++ks) {
            short8 af[4];
            #pragma unroll
            for (int mt = 0; mt < 4; ++mt)
                af[mt] = *(const short8*)&As[swz64(wr * 64 + mt * 16 + l15,
                                                   ks * 64 + hi4 * 16)];
            __builtin_amdgcn_s_setprio(1);
            #pragma unroll
            for (int nt = 0; nt < 4; ++nt) {
                const short8 bf = *(const short8*)&Bs[swz64(wc * 64 + nt * 16 + l15,
                                                            ks * 64 + hi4 * 16)];
                #pragma unroll
                for (int mt = 0; mt < 4; ++mt)
                    acc[mt][nt] = MFMA16(af[mt], bf, acc[mt][nt]);
            }
            __builtin_amdgcn_s_setprio(0);
        }
        __syncthreads();
    }

    #pragma unroll
    for (int mt = 0; mt < 4; ++mt) {
        #pragma unroll
        for (int nt = 0; nt < 4; ++nt) {
            const int colt = nb * 128 + wc * 64 + nt * 16 + l15;
            #pragma unroll
            for (int r = 0; r < 4; ++r) {
                const int row = mb * 128 + wr * 64 + mt * 16 + hi4 * 4 + r;
                if (F32OUT) {
                    of32[(size_t)row * 512 + colt] = acc[mt][nt][r];
                } else {
                    const int mat = colt >> 9, cc = colt & 511;
                    obf[(size_t)mat * 33554432 + (size_t)row * 512 + cc] =
                        f2bf(acc[mt][nt][r]);
                }
            }
        }
    }
}

// ---------------------------------------------------------------------------
// Attention v3: one block per (t,h), 512 thr = 8 waves, wave owns 32 Q-rows.
// K is read GLOBAL-DIRECT in the flash loop (qkvb slices are L2/L3-resident;
// Common-mistake #7: LDS-staging cache-fit data is pure overhead). Only V
// (needs transpose) and P (wave-private) live in LDS: 48 KB -> 3 blocks/CU.
// Single __syncthreads() in the whole kernel (after V staging).
// Writes bf16 attn-out into the Q region of qkvb (rows it already read);
// doswz pre-swizzles columns so the output feeds gemm_glds directly.
// ---------------------------------------------------------------------------
__global__ __launch_bounds__(512, 4) void attn_split(
    unsigned short* __restrict__ qkvb,
    const int* __restrict__ gid,
    int doswz)
{
    __shared__ unsigned short Vt[64 * 256];    // 32 KB, swz256
    __shared__ unsigned short Ps[256 * 32];    // 16 KB, swz32 (per-wave slices)

    const int th = blockIdx.x;
    const int t = th >> 3, h = th & 7;
    const int tid  = threadIdx.x;
    const int lane = tid & 63;
    const int w    = tid >> 6;        // 0..7
    const int l15  = lane & 15;
    const int hi4  = lane >> 4;
    const int wrow = w << 5;          // 32 rows/wave

    const size_t rowbase = (size_t)t * 256 * 512 + h * 64;
    unsigned short* __restrict__ qb = qkvb + rowbase;
    const unsigned short* __restrict__ kbp = qkvb + 33554432ull + rowbase;
    const unsigned short* __restrict__ vbp = qkvb + 67108864ull + rowbase;

    // ---- stage V transposed directly from global (coalesced dword reads) ----
    {
        const int d2 = (tid & 31) * 2;    // even d
        const int jg = tid >> 5;          // 0..15, 16-row j block
        unsigned int vv[16];
        #pragma unroll
        for (int jj = 0; jj < 16; ++jj)
            vv[jj] = *(const unsigned int*)(vbp + (size_t)(jg * 16 + jj) * 512 + d2);
        short8 a0, a1, b0, b1;
        #pragma unroll
        for (int jj = 0; jj < 8; ++jj) {
            a0[jj] = (short)(vv[jj] & 0xFFFFu);
            b0[jj] = (short)(vv[jj] >> 16);
            a1[jj] = (short)(vv[8 + jj] & 0xFFFFu);
            b1[jj] = (short)(vv[8 + jj] >> 16);
        }
        *(short8*)&Vt[swz256(d2,     jg * 32)]      = a0;
        *(short8*)&Vt[swz256(d2,     jg * 32 + 16)] = a1;
        *(short8*)&Vt[swz256(d2 + 1, jg * 32)]      = b0;
        *(short8*)&Vt[swz256(d2 + 1, jg * 32 + 16)] = b1;
    }
    // ---- Q fragments straight from global (2 m-frags) ----
    short8 qf[2][2];
    #pragma unroll
    for (int a = 0; a < 2; ++a)
        #pragma unroll
        for (int ks = 0; ks < 2; ++ks)
            qf[a][ks] = *(const short8*)(qb + (size_t)(wrow + a * 16 + l15) * 512 +
                                          ks * 32 + hi4 * 8);

    // ---- group info: binary search on sorted gid (no LDS) ----
    int rg[2][4];
    #pragma unroll
    for (int a = 0; a < 2; ++a)
        #pragma unroll
        for (int r = 0; r < 4; ++r)
            rg[a][r] = gid[wrow + a * 16 + hi4 * 4 + r];
    const int gfirst = gid[wrow], glast = gid[wrow + 31];
    int lo = 0, hi2 = 256;
    while (lo < hi2) { const int mid = (lo + hi2) >> 1;
        if (gid[mid] < gfirst) lo = mid + 1; else hi2 = mid; }
    const int klo = lo;
    lo = 0; hi2 = 256;
    while (lo < hi2) { const int mid = (lo + hi2) >> 1;
        if (gid[mid] <= glast) lo = mid + 1; else hi2 = mid; }
    const int khi = lo - 1;

    __syncthreads();   // V staged; the ONLY block-wide barrier

    // ---- group-restricted flash loop, KVBLK=32, K global-direct ----
    f32x4 o[2][4];
    float mrun[2][4], lrun[2][4];
    #pragma unroll
    for (int a = 0; a < 2; ++a)
        #pragma unroll
        for (int n = 0; n < 4; ++n)
            o[a][n] = (f32x4){0.f, 0.f, 0.f, 0.f};
    #pragma unroll
    for (int a = 0; a < 2; ++a)
        #pragma unroll
        for (int r = 0; r < 4; ++r) { mrun[a][r] = -3.0e38f; lrun[a][r] = 0.f; }

    for (int kc = klo & ~31; kc <= khi; kc += 32) {
        // S chunk = Q @ K^T : 8 MFMA, K frags straight from global (L2-hit)
        f32x4 sfr[2][2];
        __builtin_amdgcn_s_setprio(1);
        #pragma unroll
        for (int n = 0; n < 2; ++n) {
            const unsigned short* krp = kbp + (size_t)(kc + n * 16 + l15) * 512;
            const short8 kf0 = *(const short8*)(krp + hi4 * 8);
            const short8 kf1 = *(const short8*)(krp + 32 + hi4 * 8);
            #pragma unroll
            for (int a = 0; a < 2; ++a) {
                f32x4 z = (f32x4){0.f, 0.f, 0.f, 0.f};
                z = MFMA16(qf[a][0], kf0, z);
                z = MFMA16(qf[a][1], kf1, z);
                sfr[a][n] = z;
            }
        }
        __builtin_amdgcn_s_setprio(0);
        int cg[2];
        #pragma unroll
        for (int n = 0; n < 2; ++n) cg[n] = gid[kc + n * 16 + l15];

        #pragma unroll
        for (int a = 0; a < 2; ++a) {
            #pragma unroll
            for (int r = 0; r < 4; ++r) {
                const int gr = rg[a][r];
                float sv[2];
                float smax = -3.0e38f;
                #pragma unroll
                for (int n = 0; n < 2; ++n) {
                    float x = sfr[a][n][r] * 0.125f;   // 1/sqrt(64)
                    x = (cg[n] == gr) ? x : -3.0e38f;
                    sv[n] = x;
                    smax = fmaxf(smax, x);
                }
                smax = fmaxf(smax, __shfl_xor(smax, 1));
                smax = fmaxf(smax, __shfl_xor(smax, 2));
                smax = fmaxf(smax, __shfl_xor(smax, 4));
                smax = fmaxf(smax, __shfl_xor(smax, 8));
                const float newm = fmaxf(mrun[a][r], smax);
                const float corr = __expf(mrun[a][r] - newm);
                float ps = 0.f;
                unsigned short pb[2];
                #pragma unroll
                for (int n = 0; n < 2; ++n) {
                    const float p = (sv[n] > -1.0e38f) ? __expf(sv[n] - newm) : 0.f;
                    ps += p;
                    pb[n] = f2bf(p);
                }
                ps += __shfl_xor(ps, 1); ps += __shfl_xor(ps, 2);
                ps += __shfl_xor(ps, 4); ps += __shfl_xor(ps, 8);
                lrun[a][r] = lrun[a][r] * corr + ps;
                mrun[a][r] = newm;
                #pragma unroll
                for (int n = 0; n < 4; ++n) o[a][n][r] *= corr;
                const int prow = wrow + a * 16 + hi4 * 4 + r;
                #pragma unroll
                for (int n = 0; n < 2; ++n)
                    Ps[swz32(prow, (n * 16 + l15) * 2)] = pb[n];
            }
        }

        // PV: O += P @ V : 8 MFMA (wave-private P, no barrier needed)
        __builtin_amdgcn_s_setprio(1);
        #pragma unroll
        for (int a = 0; a < 2; ++a) {
            const short8 pa = *(const short8*)&Ps[swz32(wrow + a * 16 + l15, hi4 * 16)];
            #pragma unroll
            for (int n = 0; n < 4; ++n) {
                const short8 vb = *(const short8*)&Vt[swz256(n * 16 + l15,
                                                             (kc + hi4 * 8) * 2)];
                o[a][n] = MFMA16(pa, vb, o[a][n]);
            }
        }
        __builtin_amdgcn_s_setprio(0);
    }

    #pragma unroll
    for (int a = 0; a < 2; ++a) {
        #pragma unroll
        for (int r = 0; r < 4; ++r) {
            const int row = wrow + a * 16 + hi4 * 4 + r;
            const float inv = 1.0f / lrun[a][r];
            const int rsw = doswz ? ((row & 7) * 8) : 0;
            #pragma unroll
            for (int n = 0; n < 4; ++n) {
                const int cc = n * 16 + l15;
                qb[(size_t)row * 512 + (cc ^ rsw)] = f2bf(o[a][n][r] * inv);
            }
        }
    }
}

// ---------------------------------------------------------------------------
// QKV GEMM (middle path, round-6): reg-staged, swizzled LDS. Unchanged.
// ---------------------------------------------------------------------------
__global__ __launch_bounds__(1024, 4) void qkv_gemm2(
    const float* __restrict__ hs,
    const unsigned short* __restrict__ wt,
    unsigned short* __restrict__ qkvb)
{
    __shared__ unsigned short As[128 * 64];
    __shared__ unsigned short Bts[512 * 64];

    const int orig = blockIdx.x;
    const int wg = (orig & 7) * 192 + (orig >> 3);
    const int mb = wg / 3;
    const int nb = wg - mb * 3;

    const int tid  = threadIdx.x;
    const int lane = tid & 63;
    const int w    = tid >> 6;
    const int l15  = lane & 15;
    const int hi4  = lane >> 4;
    const int wr   = w >> 3;
    const int wc   = w & 7;

    f32x4 acc[4][4];
    #pragma unroll
    for (int mt = 0; mt < 4; ++mt)
        #pragma unroll
        for (int nt = 0; nt < 4; ++nt)
            acc[mt][nt] = (f32x4){0.f, 0.f, 0.f, 0.f};

    const int ar = tid >> 3, aq = tid & 7;
    const int bc = tid >> 1, bh = tid & 1;
    const float* __restrict__ asrc = hs + ((size_t)mb * 128 + ar) * 512 + aq * 8;
    const unsigned short* __restrict__ bsrc =
        wt + ((size_t)nb * 512 + bc) * 512 + bh * 32;

    float4 a0, a1;
    short8 b8[4];
    a0 = *(const float4*)asrc;
    a1 = *(const float4*)(asrc + 4);
    #pragma unroll
    for (int q = 0; q < 4; ++q) b8[q] = *(const short8*)(bsrc + q * 8);

    for (int kb = 0; kb < 512; kb += 64) {
        *(short8*)&As[swz64(ar, aq * 16)] = pack8(a0, a1);
        #pragma unroll
        for (int q = 0; q < 4; ++q)
            *(short8*)&Bts[swz64(bc, bh * 64 + q * 16)] = b8[q];
        __syncthreads();
        if (kb < 448) {
            const int kn = kb + 64;
            a0 = *(const float4*)(asrc + kn);
            a1 = *(const float4*)(asrc + kn + 4);
            #pragma unroll
            for (int q = 0; q < 4; ++q)
                b8[q] = *(const short8*)(bsrc + kn + q * 8);
        }
        #pragma unroll
        for (int ks = 0; ks < 2; ++ks) {
            short8 af[4];
            #pragma unroll
            for (int mt = 0; mt < 4; ++mt)
                af[mt] = *(const short8*)&As[swz64(wr * 64 + mt * 16 + l15,
                                                   ks * 64 + hi4 * 16)];
            __builtin_amdgcn_s_setprio(1);
            #pragma unroll
            for (int nt = 0; nt < 4; ++nt) {
                const short8 bf = *(const short8*)&Bts[swz64(wc * 64 + nt * 16 + l15,
                                                             ks * 64 + hi4 * 16)];
                #pragma unroll
                for (int mt = 0; mt < 4; ++mt)
                    acc[mt][nt] = MFMA16(af[mt], bf, acc[mt][nt]);
            }
            __builtin_amdgcn_s_setprio(0);
        }
        __syncthreads();
    }

    unsigned short* __restrict__ dst = qkvb + (size_t)nb * 33554432ull;
    #pragma unroll
    for (int mt = 0; mt < 4; ++mt) {
        #pragma unroll
        for (int nt = 0; nt < 4; ++nt) {
            const int col = wc * 64 + nt * 16 + l15;
            #pragma unroll
            for (int r = 0; r < 4; ++r) {
                const int row = mb * 128 + wr * 64 + mt * 16 + hi4 * 4 + r;
                dst[(size_t)row * 512 + col] = f2bf(acc[mt][nt][r]);
            }
        }
    }
}

// ---------------------------------------------------------------------------
// FALLBACK (ws tiny): round-4 fused QKV+attention, writes f32 attn-out to out.
// ---------------------------------------------------------------------------
__global__ __launch_bounds__(1024, 4) void qkv_attn_mfma(
    const float* __restrict__ hs,
    const int*   __restrict__ gid,
    const float* __restrict__ Wq, const float* __restrict__ Wk,
    const float* __restrict__ Wv,
    float*       __restrict__ out)
{
    __shared__ unsigned short Xs[256 * 64];
    __shared__ unsigned short Wsh[192 * 64];
    __shared__ unsigned short Ksh[256 * 64];
    __shared__ unsigned short Vt[64 * 256];
    __shared__ unsigned short XP[256 * 64];
    __shared__ int sgid[256];
    __shared__ int glo[16], ghi[16];

    const int bid = blockIdx.x;
    const int h   = (bid & 63) >> 3;
    const int t   = ((bid >> 6) << 3) + (bid & 7);

    const int tid  = threadIdx.x;
    const int lane = tid & 63;
    const int w    = tid >> 6;
    const int l15  = lane & 15;
    const int hi4  = lane >> 4;
    const int mg   = w & 3;
    const int ng   = w >> 2;

    if (tid < 16) { glo[tid] = 256; ghi[tid] = -1; }
    __syncthreads();
    if (tid < 256) {
        const int g = gid[tid];
        sgid[tid] = g;
        atomicMin(&glo[g], tid);
        atomicMax(&ghi[g], tid);
    }

    const float* __restrict__ Xbase = hs + (size_t)t * (256 * 512);

    const int xr = tid >> 2, xq = tid & 3;
    const bool doW = tid < 768;
    const int wc = tid >> 2;
    const int wq = tid & 3;
    const int wmat = wc >> 6, wcol = wc & 63;
    const float* __restrict__ wfsrc =
        (wmat == 0) ? Wq : (wmat == 1) ? Wk : Wv;

    f32x4 acc[4][3];
    #pragma unroll
    for (int mt = 0; mt < 4; ++mt)
        #pragma unroll
        for (int nt = 0; nt < 3; ++nt)
            acc[mt][nt] = (f32x4){0.f, 0.f, 0.f, 0.f};

    float4 xf[4];
    short8 w8[2];
    {
        const float* s = Xbase + (size_t)xr * 512 + xq * 16;
        xf[0] = *(const float4*)(s + 0);  xf[1] = *(const float4*)(s + 4);
        xf[2] = *(const float4*)(s + 8);  xf[3] = *(const float4*)(s + 12);
        if (doW) {
            #pragma unroll
            for (int b = 0; b < 2; ++b)
                #pragma unroll
                for (int j = 0; j < 8; ++j)
                    w8[b][j] = (short)f2bf(
                        wfsrc[(size_t)(wq * 16 + b * 8 + j) * 512 + h * 64 + wcol]);
        }
    }

    for (int kb = 0; kb < 512; kb += 64) {
        *(short8*)&Xs[swz64(xr, xq * 32 + 0)]  = pack8(xf[0], xf[1]);
        *(short8*)&Xs[swz64(xr, xq * 32 + 16)] = pack8(xf[2], xf[3]);
        if (doW) {
            *(short8*)&Wsh[swz64(wc, wq * 32 + 0)]  = w8[0];
            *(short8*)&Wsh[swz64(wc, wq * 32 + 16)] = w8[1];
        }
        __syncthreads();
        if (kb < 448) {
            const int kn = kb + 64;
            const float* s = Xbase + (size_t)xr * 512 + kn + xq * 16;
            xf[0] = *(const float4*)(s + 0);  xf[1] = *(const float4*)(s + 4);
            xf[2] = *(const float4*)(s + 8);  xf[3] = *(const float4*)(s + 12);
            if (doW) {
                #pragma unroll
                for (int b = 0; b < 2; ++b)
                    #pragma unroll
                    for (int j = 0; j < 8; ++j)
                        w8[b][j] = (short)f2bf(
                            wfsrc[(size_t)(kn + wq * 16 + b * 8 + j) * 512 + h * 64 + wcol]);
            }
        }
        #pragma unroll
        for (int ks = 0; ks < 2; ++ks) {
            short8 af[4];
            #pragma unroll
            for (int mt = 0; mt < 4; ++mt)
                af[mt] = *(const short8*)&Xs[swz64(mg * 64 + mt * 16 + l15,
                                                   ks * 64 + hi4 * 16)];
            __builtin_amdgcn_s_setprio(1);
            #pragma unroll
            for (int nt = 0; nt < 3; ++nt) {
                const short8 bf = *(const short8*)&Wsh[swz64(ng * 48 + nt * 16 + l15,
                                                             ks * 64 + hi4 * 16)];
                #pragma unroll
                for (int mt = 0; mt < 4; ++mt)
                    acc[mt][nt] = MFMA16(af[mt], bf, acc[mt][nt]);
            }
            __builtin_amdgcn_s_setprio(0);
        }
        __syncthreads();
    }

    #pragma unroll
    for (int nt = 0; nt < 3; ++nt) {
        const int c0 = (ng * 3 + nt) * 16;
        const int m  = c0 >> 6;
        const int d0 = c0 & 63;
        #pragma unroll
        for (int mt = 0; mt < 4; ++mt) {
            const int rowb = mg * 64 + mt * 16 + hi4 * 4;
            if (m == 0) {
                #pragma unroll
                for (int r = 0; r < 4; ++r)
                    XP[swz64(rowb + r, (d0 + l15) * 2)] = f2bf(acc[mt][nt][r]);
            } else if (m == 1) {
                #pragma unroll
                for (int r = 0; r < 4; ++r)
                    Ksh[swz64(rowb + r, (d0 + l15) * 2)] = f2bf(acc[mt][nt][r]);
            } else {
                short4v vv;
                #pragma unroll
                for (int r = 0; r < 4; ++r) vv[r] = (short)f2bf(acc[mt][nt][r]);
                *(short4v*)&Vt[swz256(d0 + l15, rowb * 2)] = vv;
            }
        }
    }
    __syncthreads();

    const int wrow = w << 4;
    int rg[4];
    #pragma unroll
    for (int r = 0; r < 4; ++r) rg[r] = sgid[wrow + hi4 * 4 + r];
    const int klo = glo[sgid[wrow]];
    const int khi = ghi[sgid[wrow + 15]];

    short8 qf[2];
    #pragma unroll
    for (int ks = 0; ks < 2; ++ks)
        qf[ks] = *(const short8*)&XP[swz64(wrow + l15, ks * 64 + hi4 * 16)];

    f32x4 o[4];
    float mrun[4], lrun[4];
    #pragma unroll
    for (int n = 0; n < 4; ++n) o[n] = (f32x4){0.f, 0.f, 0.f, 0.f};
    #pragma unroll
    for (int r = 0; r < 4; ++r) { mrun[r] = -3.0e38f; lrun[r] = 0.f; }

    for (int kc = klo & ~63; kc <= khi; kc += 64) {
        f32x4 sfr[4];
        __builtin_amdgcn_s_setprio(1);
        #pragma unroll
        for (int n = 0; n < 4; ++n) {
            const int krow = kc + n * 16 + l15;
            const short8 kf0 = *(const short8*)&Ksh[swz64(krow, hi4 * 16)];
            const short8 kf1 = *(const short8*)&Ksh[swz64(krow, 64 + hi4 * 16)];
            f32x4 z = (f32x4){0.f, 0.f, 0.f, 0.f};
            z = MFMA16(qf[0], kf0, z);
            z = MFMA16(qf[1], kf1, z);
            sfr[n] = z;
        }
        __builtin_amdgcn_s_setprio(0);
        int cg[4];
        #pragma unroll
        for (int n = 0; n < 4; ++n) cg[n] = sgid[kc + n * 16 + l15];

        #pragma unroll
        for (int r = 0; r < 4; ++r) {
            const int gr = rg[r];
            float sv[4];
            float smax = -3.0e38f;
            #pragma unroll
            for (int n = 0; n < 4; ++n) {
                float x = sfr[n][r] * 0.125f;
                x = (cg[n] == gr) ? x : -3.0e38f;
                sv[n] = x;
                smax = fmaxf(smax, x);
            }
            smax = fmaxf(smax, __shfl_xor(smax, 1));
            smax = fmaxf(smax, __shfl_xor(smax, 2));
            smax = fmaxf(smax, __shfl_xor(smax, 4));
            smax = fmaxf(smax, __shfl_xor(smax, 8));
            const float newm = fmaxf(mrun[r], smax);
            const float corr = __expf(mrun[r] - newm);
            float ps = 0.f;
            unsigned short pb[4];
            #pragma unroll
            for (int n = 0; n < 4; ++n) {
                const float p = (sv[n] > -1.0e38f) ? __expf(sv[n] - newm) : 0.f;
                ps += p;
                pb[n] = f2bf(p);
            }
            ps += __shfl_xor(ps, 1); ps += __shfl_xor(ps, 2);
            ps += __shfl_xor(ps, 4); ps += __shfl_xor(ps, 8);
            lrun[r] = lrun[r] * corr + ps;
            mrun[r] = newm;
            #pragma unroll
            for (int n = 0; n < 4; ++n) o[n][r] *= corr;
            const int prow = wrow + hi4 * 4 + r;
            #pragma unroll
            for (int n = 0; n < 4; ++n)
                XP[swz64(prow, (n * 16 + l15) * 2)] = pb[n];
        }

        const short8 pa0 = *(const short8*)&XP[swz64(wrow + l15, hi4 * 16)];
        const short8 pa1 = *(const short8*)&XP[swz64(wrow + l15, 64 + hi4 * 16)];
        __builtin_amdgcn_s_setprio(1);
        #pragma unroll
        for (int n = 0; n < 4; ++n) {
            const short8 vb0 = *(const short8*)&Vt[swz256(n * 16 + l15, (kc + hi4 * 8) * 2)];
            const short8 vb1 = *(const short8*)&Vt[swz256(n * 16 + l15, (kc + 32 + hi4 * 8) * 2)];
            o[n] = MFMA16(pa0, vb0, o[n]);
            o[n] = MFMA16(pa1, vb1, o[n]);
        }
        __builtin_amdgcn_s_setprio(0);
    }

    float* __restrict__ op = out + (size_t)t * (256 * 512) + h * 64;
    #pragma unroll
    for (int r = 0; r < 4; ++r) {
        const int row = wrow + hi4 * 4 + r;
        const float inv = 1.0f / lrun[r];
        #pragma unroll
        for (int n = 0; n < 4; ++n)
            op[(size_t)row * 512 + n * 16 + l15] = o[n][r] * inv;
    }
}

// ---------------------------------------------------------------------------
// O-projection (middle/fallback paths): A from bf16 abuf or f32 out in-place.
// ---------------------------------------------------------------------------
__global__ __launch_bounds__(1024, 4) void oproj_mfma(
    const float* __restrict__ Wo,
    const unsigned short* __restrict__ wot,
    const unsigned short* __restrict__ abuf,
    float* __restrict__ out)
{
    __shared__ unsigned short As[128 * 40];
    __shared__ unsigned short Bts[512 * 40];

    const int tid  = threadIdx.x;
    const int lane = tid & 63;
    const int w    = tid >> 6;
    const int l15  = lane & 15;
    const int hi4  = lane >> 4;
    const int wr   = w >> 2;
    const int wc   = w & 3;
    const size_t r0 = (size_t)blockIdx.x * 128;

    f32x4 acc[2][8];
    #pragma unroll
    for (int m = 0; m < 2; ++m)
        #pragma unroll
        for (int n = 0; n < 8; ++n)
            acc[m][n] = (f32x4){0.f, 0.f, 0.f, 0.f};

    const bool isA = tid < 512;
    const int bn = tid & 511;
    const int ai = bn >> 2, aq = bn & 3;

    float4 af0, af1;
    short8 a8;
    short8 b8[4];

    if (isA) {
        if (abuf) {
            a8 = *(const short8*)(abuf + (r0 + ai) * 512 + aq * 8);
        } else {
            const float* s = out + (r0 + ai) * 512 + aq * 8;
            af0 = *(const float4*)s; af1 = *(const float4*)(s + 4);
        }
    } else {
        if (wot) {
            #pragma unroll
            for (int q = 0; q < 4; ++q)
                b8[q] = *(const short8*)(wot + (size_t)bn * 512 + q * 8);
        } else {
            #pragma unroll
            for (int q = 0; q < 4; ++q)
                #pragma unroll
                for (int j = 0; j < 8; ++j)
                    b8[q][j] = (short)f2bf(Wo[(size_t)(q * 8 + j) * 512 + bn]);
        }
    }

    for (int kb = 0; kb < 512; kb += 32) {
        if (isA) *(short8*)&As[ai * 40 + aq * 8] = abuf ? a8 : pack8(af0, af1);
        else {
            #pragma unroll
            for (int q = 0; q < 4; ++q)
                *(short8*)&Bts[bn * 40 + q * 8] = b8[q];
        }
        __syncthreads();
        if (kb < 480) {
            const int kn = kb + 32;
            if (isA) {
                if (abuf) {
                    a8 = *(const short8*)(abuf + (r0 + ai) * 512 + kn + aq * 8);
                } else {
                    const float* s = out + (r0 + ai) * 512 + kn + aq * 8;
                    af0 = *(const float4*)s; af1 = *(const float4*)(s + 4);
                }
            } else {
                if (wot) {
                    #pragma unroll
                    for (int q = 0; q < 4; ++q)
                        b8[q] = *(const short8*)(wot + (size_t)bn * 512 + kn + q * 8);
                } else {
                    #pragma unroll
                    for (int q = 0; q < 4; ++q)
                        #pragma unroll
                        for (int j = 0; j < 8; ++j)
                            b8[q][j] = (short)f2bf(Wo[(size_t)(kn + q * 8 + j) * 512 + bn]);
                }
            }
        }
        short8 afr[2];
        #pragma unroll
        for (int m = 0; m < 2; ++m)
            afr[m] = *(const short8*)&As[(wr * 32 + m * 16 + l15) * 40 + hi4 * 8];
        __builtin_amdgcn_s_setprio(1);
        #pragma unroll
        for (int n = 0; n < 8; ++n) {
            const short8 bfr = *(const short8*)&Bts[(wc * 128 + n * 16 + l15) * 40 + hi4 * 8];
            #pragma unroll
            for (int m = 0; m < 2; ++m)
                acc[m][n] = MFMA16(afr[m], bfr, acc[m][n]);
        }
        __builtin_amdgcn_s_setprio(0);
        __syncthreads();
    }

    #pragma unroll
    for (int m = 0; m < 2; ++m)
        #pragma unroll
        for (int n = 0; n < 8; ++n)
            #pragma unroll
            for (int r = 0; r < 4; ++r)
                out[(r0 + wr * 32 + m * 16 + hi4 * 4 + r) * 512 + wc * 128 + n * 16 + l15] =
                    acc[m][n][r];
}

extern "C" void kernel_launch(void* const* d_in, const int* in_sizes, int n_in,
                              void* d_out, int out_size, void* d_ws, size_t ws_size,
                              hipStream_t stream) {
    const float* hs  = (const float*)d_in[0];
    const int*   gid = (const int*)  d_in[1];
    const float* Wq  = (const float*)d_in[2];
    const float* Wk  = (const float*)d_in[3];
    const float* Wv  = (const float*)d_in[4];
    const float* Wo  = (const float*)d_in[5];
    float* outp = (float*)d_out;

    const size_t WT_S  = 1048576;        // shorts: 4*512*512
    const size_t XB_S  = 33554432;       // 65536*512
    const size_t QKV_S = 100663296;      // 3*65536*512
    unsigned short* wt = (unsigned short*)d_ws;
    unsigned short* wot = wt + (size_t)3 * 262144;

    if (ws_size >= (WT_S + XB_S + QKV_S) * 2) {
        // fast path: pre-swizzled bf16 + glds single-buffer GEMMs
        unsigned short* xb   = wt + WT_S;
        unsigned short* qkvb = xb + XB_S;
        wprep<<<256, 256, 0, stream>>>(Wq, Wk, Wv, Wo, wt, 1);
        xprep<<<2048, 256, 0, stream>>>(hs, xb);
        gemm_glds<0><<<6144, 256, 0, stream>>>(xb, wt, qkvb, nullptr, 12);
        attn_split<<<2048, 512, 0, stream>>>(qkvb, gid, 1);
        gemm_glds<1><<<2048, 256, 0, stream>>>(qkvb, wot, nullptr, outp, 4);
    } else if (ws_size >= (WT_S + QKV_S) * 2) {
        // middle path: round-6 split (linear wt)
        unsigned short* qkvb = wt + WT_S;
        wprep<<<256, 256, 0, stream>>>(Wq, Wk, Wv, Wo, wt, 0);
        qkv_gemm2<<<1536, 1024, 0, stream>>>(hs, wt, qkvb);
        attn_split<<<2048, 512, 0, stream>>>(qkvb, gid, 0);
        oproj_mfma<<<512, 1024, 0, stream>>>(Wo, wot, qkvb, outp);
    } else {
        // fallback: fused kernel, no workspace weights
        qkv_attn_mfma<<<2048, 1024, 0, stream>>>(hs, gid, Wq, Wk, Wv, outp);
        oproj_mfma<<<512, 1024, 0, stream>>>(Wo, nullptr, nullptr, outp);
    }
}

// Round 11
// 332.416 us; speedup vs baseline: 1.0427x; 1.0427x over previous
//
#include <hip/hip_runtime.h>
#include <hip/hip_bf16.h>

typedef __attribute__((ext_vector_type(8))) short short8;
typedef __attribute__((ext_vector_type(4))) short short4v;
typedef __attribute__((ext_vector_type(4))) float f32x4;

#define MFMA16(a, b, c) __builtin_amdgcn_mfma_f32_16x16x32_bf16(a, b, c, 0, 0, 0)

__device__ __forceinline__ unsigned short f2bf(float f) {
    union { __hip_bfloat16 h; unsigned short u; } v;
    v.h = __float2bfloat16(f);
    return v.u;
}

__device__ __forceinline__ short8 pack8(float4 a, float4 b) {
    short8 p;
    p[0] = (short)f2bf(a.x); p[1] = (short)f2bf(a.y);
    p[2] = (short)f2bf(a.z); p[3] = (short)f2bf(a.w);
    p[4] = (short)f2bf(b.x); p[5] = (short)f2bf(b.y);
    p[6] = (short)f2bf(b.z); p[7] = (short)f2bf(b.w);
    return p;
}

// XOR-swizzled LDS indexing (T2): linear rows, byte ^= (row&N)<<4.
__device__ __forceinline__ int swz64(int row, int bytecol) {   // 64-short rows
    return row * 64 + ((bytecol ^ ((row & 7) << 4)) >> 1);
}
__device__ __forceinline__ int swz256(int row, int bytecol) {  // 256-short rows
    return row * 256 + ((bytecol ^ ((row & 7) << 4)) >> 1);
}
__device__ __forceinline__ int swz32(int row, int bytecol) {   // 32-short rows
    return row * 32 + ((bytecol ^ ((row & 3) << 4)) >> 1);
}

// global -> LDS direct copy, 16B/lane (m97 recipe; source pre-swizzled).
__device__ __forceinline__ void async16(void* lds_uniform, const void* gsrc) {
    __builtin_amdgcn_global_load_lds(
        (const __attribute__((address_space(1))) unsigned int*)gsrc,
        (__attribute__((address_space(3))) unsigned int*)lds_uniform,
        16, 0, 0);
}

// ---------------------------------------------------------------------------
// Weight prep: wt[m][n][k'] = W_m[k][n] bf16; swz: k' = k ^ ((n&7)*8).
// ---------------------------------------------------------------------------
__global__ __launch_bounds__(256) void wprep(
    const float* __restrict__ Wq, const float* __restrict__ Wk,
    const float* __restrict__ Wv, const float* __restrict__ Wo,
    unsigned short* __restrict__ wt, int swz)
{
    __shared__ float tile[64][65];
    const int bid = blockIdx.x;
    const int m = bid >> 6, tb = bid & 63;
    const int kr = (tb >> 3) << 6, nc = (tb & 7) << 6;
    const float* W = (m == 0) ? Wq : (m == 1) ? Wk : (m == 2) ? Wv : Wo;
    const int tid = threadIdx.x;
    for (int i = tid; i < 4096; i += 256)
        tile[i >> 6][i & 63] = W[(size_t)(kr + (i >> 6)) * 512 + nc + (i & 63)];
    __syncthreads();
    unsigned short* dst = wt + (size_t)m * 262144;
    for (int i = tid; i < 4096; i += 256) {
        const int n = nc + (i >> 6);
        const int e = i & 63;
        const int rsw = swz ? ((n & 7) * 8) : 0;
        dst[(size_t)n * 512 + kr + e] = f2bf(tile[e ^ rsw][i >> 6]);
    }
}

// ---------------------------------------------------------------------------
// X prep: xb[row][e] = bf16(hs[row][e ^ ((row&7)*8)]).
// ---------------------------------------------------------------------------
__global__ __launch_bounds__(256) void xprep(
    const float* __restrict__ hs, unsigned short* __restrict__ xb)
{
    const long long total = 4194304;   // 65536*512/8
    for (long long g = (long long)blockIdx.x * 256 + threadIdx.x; g < total;
         g += (long long)gridDim.x * 256) {
        const int row = (int)(g >> 6);
        const int e0  = ((int)g & 63) * 8;
        const int src = e0 ^ ((row & 7) * 8);
        const float* s = hs + (size_t)row * 512 + src;
        const float4 f0 = *(const float4*)s;
        const float4 f1 = *(const float4*)(s + 4);
        *(short8*)(xb + (size_t)row * 512 + e0) = pack8(f0, f1);
    }
}

// ---------------------------------------------------------------------------
// 256x256 counted-vmcnt GEMM (T3+T4-derived, race-free variant).
// BM=BN=256, BK=64, 512 thr = 8 waves (2 wr x 4 wc), wave tile 128x64
// (acc[8][4], ds:MFMA ratio 0.375). LDS: A dbuf 2x32KB + B tri-buf 3x32KB
// = 160 KB (1 block/CU; AITER attn uses 160KB on this chip).
// Schedule per K-tile t (4 phases, m-pair p):
//   phase p: ds_read A-pair (4 b128) [+ B all (8 b128) at p==0]
//            stage 2 glds: A(t+1) at p<2 (-> Abuf^1), B(t+2) at p>=2
//            (-> Bbuf[(t+2)%3]; never a buffer being read -> race-free)
//            s_barrier; 16 MFMA (setprio); s_barrier
//   boundary: s_waitcnt vmcnt(4)  (only B(t+2) outstanding -> COUNTED,
//             A(t+1)/B(t+1) are older and forced landed); vmcnt(0) only
//             at the last boundary. Then s_barrier.
// A/B bf16 PRE-SWIZZLED. F32OUT=0: bf16 -> qkvb; F32OUT=1: f32 -> of32.
// ---------------------------------------------------------------------------
template<int F32OUT>
__global__ __launch_bounds__(512, 2) void gemm256(
    const unsigned short* __restrict__ A,
    const unsigned short* __restrict__ B,
    unsigned short* __restrict__ obf,
    float* __restrict__ of32,
    int nbcnt)
{
    __shared__ unsigned short Ash[2][256 * 64];   // 64 KB
    __shared__ unsigned short Bsh[3][256 * 64];   // 96 KB

    const int orig  = blockIdx.x;
    const int chunk = gridDim.x >> 3;
    const int wg = (orig & 7) * chunk + (orig >> 3);
    const int mb = wg / nbcnt;
    const int nb = wg - mb * nbcnt;

    const int tid  = threadIdx.x;
    const int lane = tid & 63;
    const int w    = tid >> 6;        // 0..7
    const int l15  = lane & 15;
    const int hi4  = lane >> 4;
    const int wr   = w >> 2;          // 0..1: 128-row half
    const int wc   = w & 3;           // 0..3: 64-col strip

    f32x4 acc[8][4];
    #pragma unroll
    for (int m = 0; m < 8; ++m)
        #pragma unroll
        for (int n = 0; n < 4; ++n)
            acc[m][n] = (f32x4){0.f, 0.f, 0.f, 0.f};

    const char* __restrict__ Ab = (const char*)(A + (size_t)mb * 256 * 512);
    const char* __restrict__ Bb = (const char*)(B + (size_t)nb * 256 * 512);

    // stage 2 of this wave's 4 glds for one 32KB tile (j2 = 0 or 1)
    auto STAGE_A = [&](int buf, int kt, int j2) {
        #pragma unroll
        for (int j = 0; j < 2; ++j) {
            const int c = w * 4 + j2 * 2 + j;         // chunk 0..31 (1KB each)
            const int sbyte = c * 1024;               // wave-uniform LDS base
            const int s = sbyte + lane * 16;
            const int row = s >> 7, colb = s & 127;   // [256][64] bf16 rows
            async16((char*)&Ash[buf][0] + sbyte,
                    Ab + (size_t)row * 1024 + (size_t)kt * 128 + colb);
        }
    };
    auto STAGE_B = [&](int buf, int kt, int j2) {
        #pragma unroll
        for (int j = 0; j < 2; ++j) {
            const int c = w * 4 + j2 * 2 + j;
            const int sbyte = c * 1024;
            const int s = sbyte + lane * 16;
            const int row = s >> 7, colb = s & 127;
            async16((char*)&Bsh[buf][0] + sbyte,
                    Bb + (size_t)row * 1024 + (size_t)kt * 128 + colb);
        }
    };

    // prologue: A(0), B(0), B(1); newest 4 insts = B(1) -> vmcnt(4)
    STAGE_A(0, 0, 0); STAGE_A(0, 0, 1);
    STAGE_B(0, 0, 0); STAGE_B(0, 0, 1);
    STAGE_B(1, 1, 0); STAGE_B(1, 1, 1);
    asm volatile("s_waitcnt vmcnt(4)" ::: "memory");
    __builtin_amdgcn_s_barrier();

    short8 bfr[4][2];

    for (int t = 0; t < 8; ++t) {
        const int ab = t & 1;
        const int bb = t % 3;
        #pragma unroll
        for (int p = 0; p < 4; ++p) {
            short8 af[2][2];
            #pragma unroll
            for (int mi = 0; mi < 2; ++mi) {
                const int row = wr * 128 + (p * 2 + mi) * 16 + l15;
                af[mi][0] = *(const short8*)&Ash[ab][swz64(row, hi4 * 16)];
                af[mi][1] = *(const short8*)&Ash[ab][swz64(row, 64 + hi4 * 16)];
            }
            if (p == 0) {
                #pragma unroll
                for (int nt = 0; nt < 4; ++nt) {
                    const int col = wc * 64 + nt * 16 + l15;
                    bfr[nt][0] = *(const short8*)&Bsh[bb][swz64(col, hi4 * 16)];
                    bfr[nt][1] = *(const short8*)&Bsh[bb][swz64(col, 64 + hi4 * 16)];
                }
            }
            if (p < 2) { if (t < 7) STAGE_A(ab ^ 1, t + 1, p); }
            else       { if (t < 6) STAGE_B((t + 2) % 3, t + 2, p - 2); }

            __builtin_amdgcn_s_barrier();
            __builtin_amdgcn_s_setprio(1);
            #pragma unroll
            for (int nt = 0; nt < 4; ++nt) {
                #pragma unroll
                for (int mi = 0; mi < 2; ++mi) {
                    const int m = p * 2 + mi;
                    acc[m][nt] = MFMA16(af[mi][0], bfr[nt][0], acc[m][nt]);
                    acc[m][nt] = MFMA16(af[mi][1], bfr[nt][1], acc[m][nt]);
                }
            }
            __builtin_amdgcn_s_setprio(0);
            if (p < 3) __builtin_amdgcn_s_barrier();
        }
        if (t < 7) {
            if (t < 6) asm volatile("s_waitcnt vmcnt(4)" ::: "memory");
            else       asm volatile("s_waitcnt vmcnt(0)" ::: "memory");
            __builtin_amdgcn_s_barrier();
        }
    }

    #pragma unroll
    for (int m = 0; m < 8; ++m) {
        #pragma unroll
        for (int nt = 0; nt < 4; ++nt) {
            const int colt = nb * 256 + wc * 64 + nt * 16 + l15;
            #pragma unroll
            for (int r = 0; r < 4; ++r) {
                const int row = mb * 256 + wr * 128 + m * 16 + hi4 * 4 + r;
                if (F32OUT) {
                    of32[(size_t)row * 512 + colt] = acc[m][nt][r];
                } else {
                    const int mat = colt >> 9, cc = colt & 511;
                    obf[(size_t)mat * 33554432 + (size_t)row * 512 + cc] =
                        f2bf(acc[m][nt][r]);
                }
            }
        }
    }
}

// ---------------------------------------------------------------------------
// Attention v3 (round-10, unchanged): one block per (t,h), 512 thr = 8 waves.
// K global-direct; V transposed in LDS (swz256); P per-wave (swz32). 48 KB.
// Writes bf16 attn-out into the Q region of qkvb; doswz pre-swizzles cols.
// ---------------------------------------------------------------------------
__global__ __launch_bounds__(512, 4) void attn_split(
    unsigned short* __restrict__ qkvb,
    const int* __restrict__ gid,
    int doswz)
{
    __shared__ unsigned short Vt[64 * 256];
    __shared__ unsigned short Ps[256 * 32];

    const int th = blockIdx.x;
    const int t = th >> 3, h = th & 7;
    const int tid  = threadIdx.x;
    const int lane = tid & 63;
    const int w    = tid >> 6;
    const int l15  = lane & 15;
    const int hi4  = lane >> 4;
    const int wrow = w << 5;

    const size_t rowbase = (size_t)t * 256 * 512 + h * 64;
    unsigned short* __restrict__ qb = qkvb + rowbase;
    const unsigned short* __restrict__ kbp = qkvb + 33554432ull + rowbase;
    const unsigned short* __restrict__ vbp = qkvb + 67108864ull + rowbase;

    {
        const int d2 = (tid & 31) * 2;
        const int jg = tid >> 5;
        unsigned int vv[16];
        #pragma unroll
        for (int jj = 0; jj < 16; ++jj)
            vv[jj] = *(const unsigned int*)(vbp + (size_t)(jg * 16 + jj) * 512 + d2);
        short8 a0, a1, b0, b1;
        #pragma unroll
        for (int jj = 0; jj < 8; ++jj) {
            a0[jj] = (short)(vv[jj] & 0xFFFFu);
            b0[jj] = (short)(vv[jj] >> 16);
            a1[jj] = (short)(vv[8 + jj] & 0xFFFFu);
            b1[jj] = (short)(vv[8 + jj] >> 16);
        }
        *(short8*)&Vt[swz256(d2,     jg * 32)]      = a0;
        *(short8*)&Vt[swz256(d2,     jg * 32 + 16)] = a1;
        *(short8*)&Vt[swz256(d2 + 1, jg * 32)]      = b0;
        *(short8*)&Vt[swz256(d2 + 1, jg * 32 + 16)] = b1;
    }
    short8 qf[2][2];
    #pragma unroll
    for (int a = 0; a < 2; ++a)
        #pragma unroll
        for (int ks = 0; ks < 2; ++ks)
            qf[a][ks] = *(const short8*)(qb + (size_t)(wrow + a * 16 + l15) * 512 +
                                          ks * 32 + hi4 * 8);

    int rg[2][4];
    #pragma unroll
    for (int a = 0; a < 2; ++a)
        #pragma unroll
        for (int r = 0; r < 4; ++r)
            rg[a][r] = gid[wrow + a * 16 + hi4 * 4 + r];
    const int gfirst = gid[wrow], glast = gid[wrow + 31];
    int lo = 0, hi2 = 256;
    while (lo < hi2) { const int mid = (lo + hi2) >> 1;
        if (gid[mid] < gfirst) lo = mid + 1; else hi2 = mid; }
    const int klo = lo;
    lo = 0; hi2 = 256;
    while (lo < hi2) { const int mid = (lo + hi2) >> 1;
        if (gid[mid] <= glast) lo = mid + 1; else hi2 = mid; }
    const int khi = lo - 1;

    __syncthreads();

    f32x4 o[2][4];
    float mrun[2][4], lrun[2][4];
    #pragma unroll
    for (int a = 0; a < 2; ++a)
        #pragma unroll
        for (int n = 0; n < 4; ++n)
            o[a][n] = (f32x4){0.f, 0.f, 0.f, 0.f};
    #pragma unroll
    for (int a = 0; a < 2; ++a)
        #pragma unroll
        for (int r = 0; r < 4; ++r) { mrun[a][r] = -3.0e38f; lrun[a][r] = 0.f; }

    for (int kc = klo & ~31; kc <= khi; kc += 32) {
        f32x4 sfr[2][2];
        __builtin_amdgcn_s_setprio(1);
        #pragma unroll
        for (int n = 0; n < 2; ++n) {
            const unsigned short* krp = kbp + (size_t)(kc + n * 16 + l15) * 512;
            const short8 kf0 = *(const short8*)(krp + hi4 * 8);
            const short8 kf1 = *(const short8*)(krp + 32 + hi4 * 8);
            #pragma unroll
            for (int a = 0; a < 2; ++a) {
                f32x4 z = (f32x4){0.f, 0.f, 0.f, 0.f};
                z = MFMA16(qf[a][0], kf0, z);
                z = MFMA16(qf[a][1], kf1, z);
                sfr[a][n] = z;
            }
        }
        __builtin_amdgcn_s_setprio(0);
        int cg[2];
        #pragma unroll
        for (int n = 0; n < 2; ++n) cg[n] = gid[kc + n * 16 + l15];

        #pragma unroll
        for (int a = 0; a < 2; ++a) {
            #pragma unroll
            for (int r = 0; r < 4; ++r) {
                const int gr = rg[a][r];
                float sv[2];
                float smax = -3.0e38f;
                #pragma unroll
                for (int n = 0; n < 2; ++n) {
                    float x = sfr[a][n][r] * 0.125f;
                    x = (cg[n] == gr) ? x : -3.0e38f;
                    sv[n] = x;
                    smax = fmaxf(smax, x);
                }
                smax = fmaxf(smax, __shfl_xor(smax, 1));
                smax = fmaxf(smax, __shfl_xor(smax, 2));
                smax = fmaxf(smax, __shfl_xor(smax, 4));
                smax = fmaxf(smax, __shfl_xor(smax, 8));
                const float newm = fmaxf(mrun[a][r], smax);
                const float corr = __expf(mrun[a][r] - newm);
                float ps = 0.f;
                unsigned short pb[2];
                #pragma unroll
                for (int n = 0; n < 2; ++n) {
                    const float p = (sv[n] > -1.0e38f) ? __expf(sv[n] - newm) : 0.f;
                    ps += p;
                    pb[n] = f2bf(p);
                }
                ps += __shfl_xor(ps, 1); ps += __shfl_xor(ps, 2);
                ps += __shfl_xor(ps, 4); ps += __shfl_xor(ps, 8);
                lrun[a][r] = lrun[a][r] * corr + ps;
                mrun[a][r] = newm;
                #pragma unroll
                for (int n = 0; n < 4; ++n) o[a][n][r] *= corr;
                const int prow = wrow + a * 16 + hi4 * 4 + r;
                #pragma unroll
                for (int n = 0; n < 2; ++n)
                    Ps[swz32(prow, (n * 16 + l15) * 2)] = pb[n];
            }
        }

        __builtin_amdgcn_s_setprio(1);
        #pragma unroll
        for (int a = 0; a < 2; ++a) {
            const short8 pa = *(const short8*)&Ps[swz32(wrow + a * 16 + l15, hi4 * 16)];
            #pragma unroll
            for (int n = 0; n < 4; ++n) {
                const short8 vb = *(const short8*)&Vt[swz256(n * 16 + l15,
                                                             (kc + hi4 * 8) * 2)];
                o[a][n] = MFMA16(pa, vb, o[a][n]);
            }
        }
        __builtin_amdgcn_s_setprio(0);
    }

    #pragma unroll
    for (int a = 0; a < 2; ++a) {
        #pragma unroll
        for (int r = 0; r < 4; ++r) {
            const int row = wrow + a * 16 + hi4 * 4 + r;
            const float inv = 1.0f / lrun[a][r];
            const int rsw = doswz ? ((row & 7) * 8) : 0;
            #pragma unroll
            for (int n = 0; n < 4; ++n) {
                const int cc = n * 16 + l15;
                qb[(size_t)row * 512 + (cc ^ rsw)] = f2bf(o[a][n][r] * inv);
            }
        }
    }
}

// ---------------------------------------------------------------------------
// QKV GEMM (middle path): reg-staged, swizzled LDS. Unchanged.
// ---------------------------------------------------------------------------
__global__ __launch_bounds__(1024, 4) void qkv_gemm2(
    const float* __restrict__ hs,
    const unsigned short* __restrict__ wt,
    unsigned short* __restrict__ qkvb)
{
    __shared__ unsigned short As[128 * 64];
    __shared__ unsigned short Bts[512 * 64];

    const int orig = blockIdx.x;
    const int wg = (orig & 7) * 192 + (orig >> 3);
    const int mb = wg / 3;
    const int nb = wg - mb * 3;

    const int tid  = threadIdx.x;
    const int lane = tid & 63;
    const int w    = tid >> 6;
    const int l15  = lane & 15;
    const int hi4  = lane >> 4;
    const int wr   = w >> 3;
    const int wc   = w & 7;

    f32x4 acc[4][4];
    #pragma unroll
    for (int mt = 0; mt < 4; ++mt)
        #pragma unroll
        for (int nt = 0; nt < 4; ++nt)
            acc[mt][nt] = (f32x4){0.f, 0.f, 0.f, 0.f};

    const int ar = tid >> 3, aq = tid & 7;
    const int bc = tid >> 1, bh = tid & 1;
    const float* __restrict__ asrc = hs + ((size_t)mb * 128 + ar) * 512 + aq * 8;
    const unsigned short* __restrict__ bsrc =
        wt + ((size_t)nb * 512 + bc) * 512 + bh * 32;

    float4 a0, a1;
    short8 b8[4];
    a0 = *(const float4*)asrc;
    a1 = *(const float4*)(asrc + 4);
    #pragma unroll
    for (int q = 0; q < 4; ++q) b8[q] = *(const short8*)(bsrc + q * 8);

    for (int kb = 0; kb < 512; kb += 64) {
        *(short8*)&As[swz64(ar, aq * 16)] = pack8(a0, a1);
        #pragma unroll
        for (int q = 0; q < 4; ++q)
            *(short8*)&Bts[swz64(bc, bh * 64 + q * 16)] = b8[q];
        __syncthreads();
        if (kb < 448) {
            const int kn = kb + 64;
            a0 = *(const float4*)(asrc + kn);
            a1 = *(const float4*)(asrc + kn + 4);
            #pragma unroll
            for (int q = 0; q < 4; ++q)
                b8[q] = *(const short8*)(bsrc + kn + q * 8);
        }
        #pragma unroll
        for (int ks = 0; ks < 2; ++ks) {
            short8 af[4];
            #pragma unroll
            for (int mt = 0; mt < 4; ++mt)
                af[mt] = *(const short8*)&As[swz64(wr * 64 + mt * 16 + l15,
                                                   ks * 64 + hi4 * 16)];
            __builtin_amdgcn_s_setprio(1);
            #pragma unroll
            for (int nt = 0; nt < 4; ++nt) {
                const short8 bf = *(const short8*)&Bts[swz64(wc * 64 + nt * 16 + l15,
                                                             ks * 64 + hi4 * 16)];
                #pragma unroll
                for (int mt = 0; mt < 4; ++mt)
                    acc[mt][nt] = MFMA16(af[mt], bf, acc[mt][nt]);
            }
            __builtin_amdgcn_s_setprio(0);
        }
        __syncthreads();
    }

    unsigned short* __restrict__ dst = qkvb + (size_t)nb * 33554432ull;
    #pragma unroll
    for (int mt = 0; mt < 4; ++mt) {
        #pragma unroll
        for (int nt = 0; nt < 4; ++nt) {
            const int col = wc * 64 + nt * 16 + l15;
            #pragma unroll
            for (int r = 0; r < 4; ++r) {
                const int row = mb * 128 + wr * 64 + mt * 16 + hi4 * 4 + r;
                dst[(size_t)row * 512 + col] = f2bf(acc[mt][nt][r]);
            }
        }
    }
}

// ---------------------------------------------------------------------------
// FALLBACK (ws tiny): fused QKV+attention, writes f32 attn-out to out.
// ---------------------------------------------------------------------------
__global__ __launch_bounds__(1024, 4) void qkv_attn_mfma(
    const float* __restrict__ hs,
    const int*   __restrict__ gid,
    const float* __restrict__ Wq, const float* __restrict__ Wk,
    const float* __restrict__ Wv,
    float*       __restrict__ out)
{
    __shared__ unsigned short Xs[256 * 64];
    __shared__ unsigned short Wsh[192 * 64];
    __shared__ unsigned short Ksh[256 * 64];
    __shared__ unsigned short Vt[64 * 256];
    __shared__ unsigned short XP[256 * 64];
    __shared__ int sgid[256];
    __shared__ int glo[16], ghi[16];

    const int bid = blockIdx.x;
    const int h   = (bid & 63) >> 3;
    const int t   = ((bid >> 6) << 3) + (bid & 7);

    const int tid  = threadIdx.x;
    const int lane = tid & 63;
    const int w    = tid >> 6;
    const int l15  = lane & 15;
    const int hi4  = lane >> 4;
    const int mg   = w & 3;
    const int ng   = w >> 2;

    if (tid < 16) { glo[tid] = 256; ghi[tid] = -1; }
    __syncthreads();
    if (tid < 256) {
        const int g = gid[tid];
        sgid[tid] = g;
        atomicMin(&glo[g], tid);
        atomicMax(&ghi[g], tid);
    }

    const float* __restrict__ Xbase = hs + (size_t)t * (256 * 512);

    const int xr = tid >> 2, xq = tid & 3;
    const bool doW = tid < 768;
    const int wc = tid >> 2;
    const int wq = tid & 3;
    const int wmat = wc >> 6, wcol = wc & 63;
    const float* __restrict__ wfsrc =
        (wmat == 0) ? Wq : (wmat == 1) ? Wk : Wv;

    f32x4 acc[4][3];
    #pragma unroll
    for (int mt = 0; mt < 4; ++mt)
        #pragma unroll
        for (int nt = 0; nt < 3; ++nt)
            acc[mt][nt] = (f32x4){0.f, 0.f, 0.f, 0.f};

    float4 xf[4];
    short8 w8[2];
    {
        const float* s = Xbase + (size_t)xr * 512 + xq * 16;
        xf[0] = *(const float4*)(s + 0);  xf[1] = *(const float4*)(s + 4);
        xf[2] = *(const float4*)(s + 8);  xf[3] = *(const float4*)(s + 12);
        if (doW) {
            #pragma unroll
            for (int b = 0; b < 2; ++b)
                #pragma unroll
                for (int j = 0; j < 8; ++j)
                    w8[b][j] = (short)f2bf(
                        wfsrc[(size_t)(wq * 16 + b * 8 + j) * 512 + h * 64 + wcol]);
        }
    }

    for (int kb = 0; kb < 512; kb += 64) {
        *(short8*)&Xs[swz64(xr, xq * 32 + 0)]  = pack8(xf[0], xf[1]);
        *(short8*)&Xs[swz64(xr, xq * 32 + 16)] = pack8(xf[2], xf[3]);
        if (doW) {
            *(short8*)&Wsh[swz64(wc, wq * 32 + 0)]  = w8[0];
            *(short8*)&Wsh[swz64(wc, wq * 32 + 16)] = w8[1];
        }
        __syncthreads();
        if (kb < 448) {
            const int kn = kb + 64;
            const float* s = Xbase + (size_t)xr * 512 + kn + xq * 16;
            xf[0] = *(const float4*)(s + 0);  xf[1] = *(const float4*)(s + 4);
            xf[2] = *(const float4*)(s + 8);  xf[3] = *(const float4*)(s + 12);
            if (doW) {
                #pragma unroll
                for (int b = 0; b < 2; ++b)
                    #pragma unroll
                    for (int j = 0; j < 8; ++j)
                        w8[b][j] = (short)f2bf(
                            wfsrc[(size_t)(kn + wq * 16 + b * 8 + j) * 512 + h * 64 + wcol]);
            }
        }
        #pragma unroll
        for (int ks = 0; ks < 2; ++ks) {
            short8 af[4];
            #pragma unroll
            for (int mt = 0; mt < 4; ++mt)
                af[mt] = *(const short8*)&Xs[swz64(mg * 64 + mt * 16 + l15,
                                                   ks * 64 + hi4 * 16)];
            __builtin_amdgcn_s_setprio(1);
            #pragma unroll
            for (int nt = 0; nt < 3; ++nt) {
                const short8 bf = *(const short8*)&Wsh[swz64(ng * 48 + nt * 16 + l15,
                                                             ks * 64 + hi4 * 16)];
                #pragma unroll
                for (int mt = 0; mt < 4; ++mt)
                    acc[mt][nt] = MFMA16(af[mt], bf, acc[mt][nt]);
            }
            __builtin_amdgcn_s_setprio(0);
        }
        __syncthreads();
    }

    #pragma unroll
    for (int nt = 0; nt < 3; ++nt) {
        const int c0 = (ng * 3 + nt) * 16;
        const int m  = c0 >> 6;
        const int d0 = c0 & 63;
        #pragma unroll
        for (int mt = 0; mt < 4; ++mt) {
            const int rowb = mg * 64 + mt * 16 + hi4 * 4;
            if (m == 0) {
                #pragma unroll
                for (int r = 0; r < 4; ++r)
                    XP[swz64(rowb + r, (d0 + l15) * 2)] = f2bf(acc[mt][nt][r]);
            } else if (m == 1) {
                #pragma unroll
                for (int r = 0; r < 4; ++r)
                    Ksh[swz64(rowb + r, (d0 + l15) * 2)] = f2bf(acc[mt][nt][r]);
            } else {
                short4v vv;
                #pragma unroll
                for (int r = 0; r < 4; ++r) vv[r] = (short)f2bf(acc[mt][nt][r]);
                *(short4v*)&Vt[swz256(d0 + l15, rowb * 2)] = vv;
            }
        }
    }
    __syncthreads();

    const int wrow = w << 4;
    int rg[4];
    #pragma unroll
    for (int r = 0; r < 4; ++r) rg[r] = sgid[wrow + hi4 * 4 + r];
    const int klo = glo[sgid[wrow]];
    const int khi = ghi[sgid[wrow + 15]];

    short8 qf[2];
    #pragma unroll
    for (int ks = 0; ks < 2; ++ks)
        qf[ks] = *(const short8*)&XP[swz64(wrow + l15, ks * 64 + hi4 * 16)];

    f32x4 o[4];
    float mrun[4], lrun[4];
    #pragma unroll
    for (int n = 0; n < 4; ++n) o[n] = (f32x4){0.f, 0.f, 0.f, 0.f};
    #pragma unroll
    for (int r = 0; r < 4; ++r) { mrun[r] = -3.0e38f; lrun[r] = 0.f; }

    for (int kc = klo & ~63; kc <= khi; kc += 64) {
        f32x4 sfr[4];
        __builtin_amdgcn_s_setprio(1);
        #pragma unroll
        for (int n = 0; n < 4; ++n) {
            const int krow = kc + n * 16 + l15;
            const short8 kf0 = *(const short8*)&Ksh[swz64(krow, hi4 * 16)];
            const short8 kf1 = *(const short8*)&Ksh[swz64(krow, 64 + hi4 * 16)];
            f32x4 z = (f32x4){0.f, 0.f, 0.f, 0.f};
            z = MFMA16(qf[0], kf0, z);
            z = MFMA16(qf[1], kf1, z);
            sfr[n] = z;
        }
        __builtin_amdgcn_s_setprio(0);
        int cg[4];
        #pragma unroll
        for (int n = 0; n < 4; ++n) cg[n] = sgid[kc + n * 16 + l15];

        #pragma unroll
        for (int r = 0; r < 4; ++r) {
            const int gr = rg[r];
            float sv[4];
            float smax = -3.0e38f;
            #pragma unroll
            for (int n = 0; n < 4; ++n) {
                float x = sfr[n][r] * 0.125f;
                x = (cg[n] == gr) ? x : -3.0e38f;
                sv[n] = x;
                smax = fmaxf(smax, x);
            }
            smax = fmaxf(smax, __shfl_xor(smax, 1));
            smax = fmaxf(smax, __shfl_xor(smax, 2));
            smax = fmaxf(smax, __shfl_xor(smax, 4));
            smax = fmaxf(smax, __shfl_xor(smax, 8));
            const float newm = fmaxf(mrun[r], smax);
            const float corr = __expf(mrun[r] - newm);
            float ps = 0.f;
            unsigned short pb[4];
            #pragma unroll
            for (int n = 0; n < 4; ++n) {
                const float p = (sv[n] > -1.0e38f) ? __expf(sv[n] - newm) : 0.f;
                ps += p;
                pb[n] = f2bf(p);
            }
            ps += __shfl_xor(ps, 1); ps += __shfl_xor(ps, 2);
            ps += __shfl_xor(ps, 4); ps += __shfl_xor(ps, 8);
            lrun[r] = lrun[r] * corr + ps;
            mrun[r] = newm;
            #pragma unroll
            for (int n = 0; n < 4; ++n) o[n][r] *= corr;
            const int prow = wrow + hi4 * 4 + r;
            #pragma unroll
            for (int n = 0; n < 4; ++n)
                XP[swz64(prow, (n * 16 + l15) * 2)] = pb[n];
        }

        const short8 pa0 = *(const short8*)&XP[swz64(wrow + l15, hi4 * 16)];
        const short8 pa1 = *(const short8*)&XP[swz64(wrow + l15, 64 + hi4 * 16)];
        __builtin_amdgcn_s_setprio(1);
        #pragma unroll
        for (int n = 0; n < 4; ++n) {
            const short8 vb0 = *(const short8*)&Vt[swz256(n * 16 + l15, (kc + hi4 * 8) * 2)];
            const short8 vb1 = *(const short8*)&Vt[swz256(n * 16 + l15, (kc + 32 + hi4 * 8) * 2)];
            o[n] = MFMA16(pa0, vb0, o[n]);
            o[n] = MFMA16(pa1, vb1, o[n]);
        }
        __builtin_amdgcn_s_setprio(0);
    }

    float* __restrict__ op = out + (size_t)t * (256 * 512) + h * 64;
    #pragma unroll
    for (int r = 0; r < 4; ++r) {
        const int row = wrow + hi4 * 4 + r;
        const float inv = 1.0f / lrun[r];
        #pragma unroll
        for (int n = 0; n < 4; ++n)
            op[(size_t)row * 512 + n * 16 + l15] = o[n][r] * inv;
    }
}

// ---------------------------------------------------------------------------
// O-projection (middle/fallback paths): A from bf16 abuf or f32 out in-place.
// ---------------------------------------------------------------------------
__global__ __launch_bounds__(1024, 4) void oproj_mfma(
    const float* __restrict__ Wo,
    const unsigned short* __restrict__ wot,
    const unsigned short* __restrict__ abuf,
    float* __restrict__ out)
{
    __shared__ unsigned short As[128 * 40];
    __shared__ unsigned short Bts[512 * 40];

    const int tid  = threadIdx.x;
    const int lane = tid & 63;
    const int w    = tid >> 6;
    const int l15  = lane & 15;
    const int hi4  = lane >> 4;
    const int wr   = w >> 2;
    const int wc   = w & 3;
    const size_t r0 = (size_t)blockIdx.x * 128;

    f32x4 acc[2][8];
    #pragma unroll
    for (int m = 0; m < 2; ++m)
        #pragma unroll
        for (int n = 0; n < 8; ++n)
            acc[m][n] = (f32x4){0.f, 0.f, 0.f, 0.f};

    const bool isA = tid < 512;
    const int bn = tid & 511;
    const int ai = bn >> 2, aq = bn & 3;

    float4 af0, af1;
    short8 a8;
    short8 b8[4];

    if (isA) {
        if (abuf) {
            a8 = *(const short8*)(abuf + (r0 + ai) * 512 + aq * 8);
        } else {
            const float* s = out + (r0 + ai) * 512 + aq * 8;
            af0 = *(const float4*)s; af1 = *(const float4*)(s + 4);
        }
    } else {
        if (wot) {
            #pragma unroll
            for (int q = 0; q < 4; ++q)
                b8[q] = *(const short8*)(wot + (size_t)bn * 512 + q * 8);
        } else {
            #pragma unroll
            for (int q = 0; q < 4; ++q)
                #pragma unroll
                for (int j = 0; j < 8; ++j)
                    b8[q][j] = (short)f2bf(Wo[(size_t)(q * 8 + j) * 512 + bn]);
        }
    }

    for (int kb = 0; kb < 512; kb += 32) {
        if (isA) *(short8*)&As[ai * 40 + aq * 8] = abuf ? a8 : pack8(af0, af1);
        else {
            #pragma unroll
            for (int q = 0; q < 4; ++q)
                *(short8*)&Bts[bn * 40 + q * 8] = b8[q];
        }
        __syncthreads();
        if (kb < 480) {
            const int kn = kb + 32;
            if (isA) {
                if (abuf) {
                    a8 = *(const short8*)(abuf + (r0 + ai) * 512 + kn + aq * 8);
                } else {
                    const float* s = out + (r0 + ai) * 512 + kn + aq * 8;
                    af0 = *(const float4*)s; af1 = *(const float4*)(s + 4);
                }
            } else {
                if (wot) {
                    #pragma unroll
                    for (int q = 0; q < 4; ++q)
                        b8[q] = *(const short8*)(wot + (size_t)bn * 512 + kn + q * 8);
                } else {
                    #pragma unroll
                    for (int q = 0; q < 4; ++q)
                        #pragma unroll
                        for (int j = 0; j < 8; ++j)
                            b8[q][j] = (short)f2bf(Wo[(size_t)(kn + q * 8 + j) * 512 + bn]);
                }
            }
        }
        short8 afr[2];
        #pragma unroll
        for (int m = 0; m < 2; ++m)
            afr[m] = *(const short8*)&As[(wr * 32 + m * 16 + l15) * 40 + hi4 * 8];
        __builtin_amdgcn_s_setprio(1);
        #pragma unroll
        for (int n = 0; n < 8; ++n) {
            const short8 bfr = *(const short8*)&Bts[(wc * 128 + n * 16 + l15) * 40 + hi4 * 8];
            #pragma unroll
            for (int m = 0; m < 2; ++m)
                acc[m][n] = MFMA16(afr[m], bfr, acc[m][n]);
        }
        __builtin_amdgcn_s_setprio(0);
        __syncthreads();
    }

    #pragma unroll
    for (int m = 0; m < 2; ++m)
        #pragma unroll
        for (int n = 0; n < 8; ++n)
            #pragma unroll
            for (int r = 0; r < 4; ++r)
                out[(r0 + wr * 32 + m * 16 + hi4 * 4 + r) * 512 + wc * 128 + n * 16 + l15] =
                    acc[m][n][r];
}

extern "C" void kernel_launch(void* const* d_in, const int* in_sizes, int n_in,
                              void* d_out, int out_size, void* d_ws, size_t ws_size,
                              hipStream_t stream) {
    const float* hs  = (const float*)d_in[0];
    const int*   gid = (const int*)  d_in[1];
    const float* Wq  = (const float*)d_in[2];
    const float* Wk  = (const float*)d_in[3];
    const float* Wv  = (const float*)d_in[4];
    const float* Wo  = (const float*)d_in[5];
    float* outp = (float*)d_out;

    const size_t WT_S  = 1048576;        // shorts: 4*512*512
    const size_t XB_S  = 33554432;       // 65536*512
    const size_t QKV_S = 100663296;      // 3*65536*512
    unsigned short* wt = (unsigned short*)d_ws;
    unsigned short* wot = wt + (size_t)3 * 262144;

    if (ws_size >= (WT_S + XB_S + QKV_S) * 2) {
        // fast path: pre-swizzled bf16 + 256x256 counted-vmcnt GEMMs
        unsigned short* xb   = wt + WT_S;
        unsigned short* qkvb = xb + XB_S;
        wprep<<<256, 256, 0, stream>>>(Wq, Wk, Wv, Wo, wt, 1);
        xprep<<<2048, 256, 0, stream>>>(hs, xb);
        gemm256<0><<<1536, 512, 0, stream>>>(xb, wt, qkvb, nullptr, 6);
        attn_split<<<2048, 512, 0, stream>>>(qkvb, gid, 1);
        gemm256<1><<<512, 512, 0, stream>>>(qkvb, wot, nullptr, outp, 2);
    } else if (ws_size >= (WT_S + QKV_S) * 2) {
        // middle path: round-6 split (linear wt)
        unsigned short* qkvb = wt + WT_S;
        wprep<<<256, 256, 0, stream>>>(Wq, Wk, Wv, Wo, wt, 0);
        qkv_gemm2<<<1536, 1024, 0, stream>>>(hs, wt, qkvb);
        attn_split<<<2048, 512, 0, stream>>>(qkvb, gid, 0);
        oproj_mfma<<<512, 1024, 0, stream>>>(Wo, wot, qkvb, outp);
    } else {
        // fallback: fused kernel, no workspace weights
        qkv_attn_mfma<<<2048, 1024, 0, stream>>>(hs, gid, Wq, Wk, Wv, outp);
        oproj_mfma<<<512, 1024, 0, stream>>>(Wo, nullptr, nullptr, outp);
    }
}